// Round 7
// baseline (535.809 us; speedup 1.0000x reference)
//
#include <hip/hip_runtime.h>
#include <math.h>

#define N_NODES_C 16384
#define N_EDGES_C 196608

typedef short bf16x8 __attribute__((ext_vector_type(8)));
typedef float f32x4 __attribute__((ext_vector_type(4)));
typedef float f32x8 __attribute__((ext_vector_type(8)));

__device__ __forceinline__ float silu_f(float x) {
  return x * __builtin_amdgcn_rcpf(1.0f + __expf(-x));
}

// ---------------- CSR build ----------------
__global__ void k_count(const int* __restrict__ rcv, int* __restrict__ counts) {
  int e = blockIdx.x * 256 + threadIdx.x;
  atomicAdd(&counts[rcv[e]], 1);
}

__global__ __launch_bounds__(1024) void k_scan(const int* __restrict__ counts,
                                               int* __restrict__ row_start,
                                               int* __restrict__ cursor) {
  __shared__ int sums[1024];
  const int tid = threadIdx.x;
  int loc[16];
  int s = 0;
#pragma unroll
  for (int i = 0; i < 16; ++i) { loc[i] = counts[tid * 16 + i]; s += loc[i]; }
  sums[tid] = s;
  __syncthreads();
  for (int off = 1; off < 1024; off <<= 1) {
    int t = (tid >= off) ? sums[tid - off] : 0;
    __syncthreads();
    sums[tid] += t;
    __syncthreads();
  }
  int excl = sums[tid] - s;
#pragma unroll
  for (int i = 0; i < 16; ++i) {
    row_start[tid * 16 + i] = excl;
    cursor[tid * 16 + i] = excl;
    excl += loc[i];
  }
  if (tid == 1023) row_start[N_NODES_C] = excl;
}

__global__ void k_fill(const int* __restrict__ rcv, int* __restrict__ cursor,
                       int* __restrict__ elist) {
  int e = blockIdx.x * 256 + threadIdx.x;
  int slot = atomicAdd(&cursor[rcv[e]], 1);
  elist[slot] = e;
}

// ---------------- node element id + embedding ----------------
__global__ void k_elem(const float* __restrict__ attrs, int* __restrict__ elem) {
  int n = blockIdx.x * 256 + threadIdx.x;
  const float* a = attrs + n * 8;
  int best = 0;
  float bv = a[0];
#pragma unroll
  for (int z = 1; z < 8; ++z) {
    if (a[z] > bv) { bv = a[z]; best = z; }
  }
  elem[n] = best;
}

__global__ void k_embed(const float* __restrict__ attrs, const float* __restrict__ Wemb,
                        float* __restrict__ scal0, float* __restrict__ nf) {
  int gid = blockIdx.x * 256 + threadIdx.x;  // N*32 threads
  int n = gid >> 5, c = gid & 31;
  float s = 0.f;
#pragma unroll
  for (int z = 0; z < 8; ++z) s = fmaf(attrs[n * 8 + z], Wemb[z * 32 + c], s);
  scal0[gid] = s;
  float* row = nf + (size_t)n * 512 + c * 16;
  *(float4*)&row[0] = make_float4(s, 0.f, 0.f, 0.f);
  *(float4*)&row[4] = make_float4(0.f, 0.f, 0.f, 0.f);
  *(float4*)&row[8] = make_float4(0.f, 0.f, 0.f, 0.f);
  *(float4*)&row[12] = make_float4(0.f, 0.f, 0.f, 0.f);
}

// ---------------- per-edge radial MLP in CSR order (+SH, +s-edge) ---------
// Wave = 32 CSR positions; 2 edges processed per t-iteration (independent
// LDS h-buffers -> 2x ILP on the serial write->read chains).
__global__ __launch_bounds__(256, 3) void k_radial(
    const float* __restrict__ pos, const float* __restrict__ shifts,
    const int* __restrict__ snd, const int* __restrict__ rcv,
    const int* __restrict__ elist, const float* __restrict__ scal,
    const float* __restrict__ W1g, const float* __restrict__ W2g,
    const float* __restrict__ W3g, unsigned short* __restrict__ h3,
    float* __restrict__ sedge, float* __restrict__ Yout, const int writeY) {
  __shared__ __align__(16) float efs[4][32][8];
  __shared__ __align__(16) float hbs[4][2][64];
  const int wid = threadIdx.x >> 6, lane = threadIdx.x & 63;
  float w1c[8], w2c[64], w3c[64];
#pragma unroll
  for (int k = 0; k < 8; ++k) w1c[k] = W1g[k * 64 + lane];
#pragma unroll
  for (int k = 0; k < 64; ++k) w2c[k] = W2g[k * 64 + lane];
#pragma unroll
  for (int k = 0; k < 64; ++k) w3c[k] = W3g[k * 64 + lane];

  const int base = (blockIdx.x * 4 + wid) * 32;

  if (lane < 32) {
    const int p = base + lane;
    const int e = elist[p];
    const int sn = snd[e], rc = rcv[e];
    const float vx = pos[rc * 3 + 0] - pos[sn * 3 + 0] + shifts[e * 3 + 0];
    const float vy = pos[rc * 3 + 1] - pos[sn * 3 + 1] + shifts[e * 3 + 1];
    const float vz = pos[rc * 3 + 2] - pos[sn * 3 + 2] + shifts[e * 3 + 2];
    const float len = __builtin_amdgcn_sqrtf(vx * vx + vy * vy + vz * vz + 1e-18f);
    const float u = len * 0.2f;  // / R_MAX
    float fc = 0.f;
    if (u < 1.0f) {
      const float u2 = u * u, u5 = u2 * u2 * u;
      fc = 1.0f - 21.0f * u5 + 35.0f * u5 * u - 15.0f * u5 * u2;
    }
    const float pref = 0.6324555320336759f * fc * __builtin_amdgcn_rcpf(fmaxf(len, 1e-9f));
    float efv[8];
#pragma unroll
    for (int k = 0; k < 8; ++k) {
      const float pin = 3.14159274f * (float)(k + 1);
      efv[k] = pref * __sinf(pin * u);
    }
    *(float4*)&efs[wid][lane][0] = make_float4(efv[0], efv[1], efv[2], efv[3]);
    *(float4*)&efs[wid][lane][4] = make_float4(efv[4], efv[5], efv[6], efv[7]);

    if (writeY) {
      const float il = __builtin_amdgcn_rcpf(len);
      const float x = vx * il, y = vy * il, z = vz * il;
      const float x2 = x * x, y2 = y * y, z2 = z * z;
      const float s3 = 1.7320508075688772f;
      const float s15 = 3.872983346207417f;
      const float s5h = 1.118033988749895f;
      const float s35_8 = 2.091650066335189f;
      const float s105 = 10.246950765959598f;
      const float s21_8 = 1.6201851746019651f;
      const float s7h = 1.3228756555322954f;
      const float s105h = 5.123475382979799f;
      float* yp = Yout + (size_t)p * 16;
      *(float4*)&yp[0] = make_float4(1.f, s3 * x, s3 * y, s3 * z);
      *(float4*)&yp[4] = make_float4(s15 * x * y, s15 * y * z, s5h * (3.f * z2 - 1.f), s15 * x * z);
      *(float4*)&yp[8] = make_float4(0.5f * s15 * (x2 - y2), s35_8 * y * (3.f * x2 - y2),
                                     s105 * x * y * z, s21_8 * y * (5.f * z2 - 1.f));
      *(float4*)&yp[12] = make_float4(s7h * z * (5.f * z2 - 3.f), s21_8 * x * (5.f * z2 - 1.f),
                                      s105h * z * (x2 - y2), s35_8 * x * (x2 - 3.f * y2));
    }
  }

  // sedge[p][32] = scal[snd[e_p]][:] ; two lanes per position
  {
    const int p2 = base + (lane >> 1);
    const int e2 = elist[p2];
    const int sn2 = snd[e2];
    const int co = (lane & 1) * 16;
    const float* sp = scal + (size_t)sn2 * 32 + co;
    float* dp = sedge + (size_t)p2 * 32 + co;
    *(float4*)&dp[0] = *(const float4*)&sp[0];
    *(float4*)&dp[4] = *(const float4*)&sp[4];
    *(float4*)&dp[8] = *(const float4*)&sp[8];
    *(float4*)&dp[12] = *(const float4*)&sp[12];
  }

  for (int t = 0; t < 16; ++t) {
    // ---- layer 1 for edges A=base+t, B=base+16+t
    const float4 eA0 = *(const float4*)&efs[wid][t][0];
    const float4 eA1 = *(const float4*)&efs[wid][t][4];
    const float4 eB0 = *(const float4*)&efs[wid][t + 16][0];
    const float4 eB1 = *(const float4*)&efs[wid][t + 16][4];
    float aA = eA0.x * w1c[0], aB = eB0.x * w1c[0];
    aA = fmaf(eA0.y, w1c[1], aA); aB = fmaf(eB0.y, w1c[1], aB);
    aA = fmaf(eA0.z, w1c[2], aA); aB = fmaf(eB0.z, w1c[2], aB);
    aA = fmaf(eA0.w, w1c[3], aA); aB = fmaf(eB0.w, w1c[3], aB);
    aA = fmaf(eA1.x, w1c[4], aA); aB = fmaf(eB1.x, w1c[4], aB);
    aA = fmaf(eA1.y, w1c[5], aA); aB = fmaf(eB1.y, w1c[5], aB);
    aA = fmaf(eA1.z, w1c[6], aA); aB = fmaf(eB1.z, w1c[6], aB);
    aA = fmaf(eA1.w, w1c[7], aA); aB = fmaf(eB1.w, w1c[7], aB);
    hbs[wid][0][lane] = silu_f(aA);
    hbs[wid][1][lane] = silu_f(aB);
    // ---- layer 2
    float pA0 = 0.f, pA1 = 0.f, pA2 = 0.f, pA3 = 0.f;
    float pB0 = 0.f, pB1 = 0.f, pB2 = 0.f, pB3 = 0.f;
#pragma unroll
    for (int k4 = 0; k4 < 16; ++k4) {
      const float4 hA = *(const float4*)&hbs[wid][0][k4 * 4];
      const float4 hB = *(const float4*)&hbs[wid][1][k4 * 4];
      pA0 = fmaf(hA.x, w2c[k4 * 4 + 0], pA0); pB0 = fmaf(hB.x, w2c[k4 * 4 + 0], pB0);
      pA1 = fmaf(hA.y, w2c[k4 * 4 + 1], pA1); pB1 = fmaf(hB.y, w2c[k4 * 4 + 1], pB1);
      pA2 = fmaf(hA.z, w2c[k4 * 4 + 2], pA2); pB2 = fmaf(hB.z, w2c[k4 * 4 + 2], pB2);
      pA3 = fmaf(hA.w, w2c[k4 * 4 + 3], pA3); pB3 = fmaf(hB.w, w2c[k4 * 4 + 3], pB3);
    }
    hbs[wid][0][lane] = silu_f((pA0 + pA1) + (pA2 + pA3));
    hbs[wid][1][lane] = silu_f((pB0 + pB1) + (pB2 + pB3));
    // ---- layer 3
    pA0 = pA1 = pA2 = pA3 = 0.f;
    pB0 = pB1 = pB2 = pB3 = 0.f;
#pragma unroll
    for (int k4 = 0; k4 < 16; ++k4) {
      const float4 hA = *(const float4*)&hbs[wid][0][k4 * 4];
      const float4 hB = *(const float4*)&hbs[wid][1][k4 * 4];
      pA0 = fmaf(hA.x, w3c[k4 * 4 + 0], pA0); pB0 = fmaf(hB.x, w3c[k4 * 4 + 0], pB0);
      pA1 = fmaf(hA.y, w3c[k4 * 4 + 1], pA1); pB1 = fmaf(hB.y, w3c[k4 * 4 + 1], pB1);
      pA2 = fmaf(hA.z, w3c[k4 * 4 + 2], pA2); pB2 = fmaf(hB.z, w3c[k4 * 4 + 2], pB2);
      pA3 = fmaf(hA.w, w3c[k4 * 4 + 3], pA3); pB3 = fmaf(hB.w, w3c[k4 * 4 + 3], pB3);
    }
    const float hvA = silu_f((pA0 + pA1) + (pA2 + pA3));
    const float hvB = silu_f((pB0 + pB1) + (pB2 + pB3));
    const unsigned hbA = __float_as_uint(hvA) & 0xFFFF0000u;
    const unsigned hbB = __float_as_uint(hvB) & 0xFFFF0000u;
    const float loA = hvA - __uint_as_float(hbA);
    const float loB = hvB - __uint_as_float(hbB);
    h3[(size_t)(base + t) * 128 + lane] = (unsigned short)(hbA >> 16);
    h3[(size_t)(base + t) * 128 + 64 + lane] = (unsigned short)(__float_as_uint(loA) >> 16);
    h3[(size_t)(base + 16 + t) * 128 + lane] = (unsigned short)(hbB >> 16);
    h3[(size_t)(base + 16 + t) * 128 + 64 + lane] = (unsigned short)(__float_as_uint(loB) >> 16);
  }
}

// ---------------- node-gathered W4 GEMM via MFMA, full-K waves ------------
// Wave owns 64 cols x K=64. B-hi frags in regs; B-lo frags in LDS (32 KB,
// loop-invariant, re-read per chunk) -> ~108 regs -> 4 waves/SIMD.
// Epilogue: direct broadcast s4 loads (no ds_bpermute). XCD-paired blocks
// (b, b+8 same XCD) share h3/Y/sedge in L2. C/D: col=lm, row=grp*4+reg.
__global__ __launch_bounds__(256, 4) void k_gather(
    const unsigned short* __restrict__ h3, const float* __restrict__ W4g,
    const float* __restrict__ Yb, const float* __restrict__ sedge,
    const int* __restrict__ row_start, float* __restrict__ agg) {
  __shared__ __align__(16) short blo_lds[4][4][2][64][8];  // [w][t][kk][lane][j]
  const int ch = (blockIdx.x >> 3) & 1;
  const int ng = ((blockIdx.x >> 4) << 3) | (blockIdx.x & 7);
  const int w = threadIdx.x >> 6, lane = threadIdx.x & 63;
  const int grp = lane >> 4, lm = lane & 15;

  bf16x8 bhi[4][2];
#pragma unroll
  for (int t = 0; t < 4; ++t) {
    const int col = ch * 256 + w * 64 + t * 16 + lm;
#pragma unroll
    for (int kk = 0; kk < 2; ++kk) {
      bf16x8 lo;
#pragma unroll
      for (int j = 0; j < 8; ++j) {
        const float wv = W4g[(kk * 32 + grp * 8 + j) * 512 + col];
        const unsigned hb = __float_as_uint(wv) & 0xFFFF0000u;
        bhi[t][kk][j] = (short)(hb >> 16);
        lo[j] = (short)(__float_as_uint(wv - __uint_as_float(hb)) >> 16);
      }
      *(bf16x8*)&blo_lds[w][t][kk][lane][0] = lo;
    }
  }
  __syncthreads();

  const int nBeg = ng * 8;
  for (int n = nBeg; n < nBeg + 8; ++n) {
    const int e0 = row_start[n], e1 = row_start[n + 1];
    float outv[4] = {0.f, 0.f, 0.f, 0.f};
    for (int p0 = e0; p0 < e1; p0 += 16) {
      bf16x8 ahi0 = {0, 0, 0, 0, 0, 0, 0, 0}, ahi1 = ahi0, alo0 = ahi0, alo1 = ahi0;
      const int pa = p0 + lm;
      if (pa < e1) {
        const unsigned short* hp = h3 + (size_t)pa * 128 + grp * 8;
        ahi0 = *(const bf16x8*)(hp);
        ahi1 = *(const bf16x8*)(hp + 32);
        alo0 = *(const bf16x8*)(hp + 64);
        alo1 = *(const bf16x8*)(hp + 96);
      }
      float ys[4][4];
#pragma unroll
      for (int r = 0; r < 4; ++r) {
        const int pr = p0 + grp * 4 + r;
        const float Yv = Yb[(size_t)pr * 16 + lm];
        const float4 s4 = *(const float4*)&sedge[(size_t)pr * 32 + ch * 16 + w * 4];
        ys[r][0] = Yv * s4.x;
        ys[r][1] = Yv * s4.y;
        ys[r][2] = Yv * s4.z;
        ys[r][3] = Yv * s4.w;
      }
#pragma unroll
      for (int t = 0; t < 4; ++t) {
        f32x4 acc = {0.f, 0.f, 0.f, 0.f};
        acc = __builtin_amdgcn_mfma_f32_16x16x32_bf16(ahi0, bhi[t][0], acc, 0, 0, 0);
        acc = __builtin_amdgcn_mfma_f32_16x16x32_bf16(ahi1, bhi[t][1], acc, 0, 0, 0);
        acc = __builtin_amdgcn_mfma_f32_16x16x32_bf16(alo0, bhi[t][0], acc, 0, 0, 0);
        acc = __builtin_amdgcn_mfma_f32_16x16x32_bf16(alo1, bhi[t][1], acc, 0, 0, 0);
        const bf16x8 bl0 = *(const bf16x8*)&blo_lds[w][t][0][lane][0];
        const bf16x8 bl1 = *(const bf16x8*)&blo_lds[w][t][1][lane][0];
        acc = __builtin_amdgcn_mfma_f32_16x16x32_bf16(ahi0, bl0, acc, 0, 0, 0);
        acc = __builtin_amdgcn_mfma_f32_16x16x32_bf16(ahi1, bl1, acc, 0, 0, 0);
        float cp = acc[0] * ys[0][t];
        cp = fmaf(acc[1], ys[1][t], cp);
        cp = fmaf(acc[2], ys[2][t], cp);
        cp = fmaf(acc[3], ys[3][t], cp);
        outv[t] += cp;
      }
    }
    const float inv12 = 1.0f / 12.0f;
#pragma unroll
    for (int t = 0; t < 4; ++t) {
      outv[t] += __shfl_xor(outv[t], 16);
      outv[t] += __shfl_xor(outv[t], 32);
      if (grp == t)
        agg[(size_t)n * 512 + ch * 256 + w * 64 + t * 16 + lm] = outv[t] * inv12;
    }
  }
}

// ---------------- per-node: Wlin, quadratic, Wprod + skip, desc out -------
__global__ __launch_bounds__(256) void k_node(
    const float* __restrict__ agg, float* __restrict__ nf,
    const float* __restrict__ Wlin, const float* __restrict__ Wprod,
    const float* __restrict__ Wskip, const float* __restrict__ w2v,
    const float* __restrict__ w3v, const int* __restrict__ elem,
    float* __restrict__ scal_out, float* __restrict__ dout, const int layer) {
  __shared__ __align__(16) float aggs[8][512];
  __shared__ __align__(16) float nfs[8][512];
  __shared__ float bs[8][544];  // pitch 17 per channel row
  const int tid = threadIdx.x;
  const int n0 = blockIdx.x * 8;
  for (int i = tid; i < 1024; i += 256) {
    const int nl = i >> 7, qq = i & 127;
    ((f32x4*)aggs)[i] = ((const f32x4*)agg)[(size_t)(n0 + nl) * 128 + qq];
    ((f32x4*)nfs)[i] = ((const f32x4*)nf)[(size_t)(n0 + nl) * 128 + qq];
  }
  __syncthreads();
  const int nl = tid >> 5, o = tid & 31;
  const int n = n0 + nl;
  constexpr int SLa[4] = {0, 1, 4, 9};
  constexpr int ELa[4] = {1, 4, 9, 16};
  float a[16];
#pragma unroll
  for (int m = 0; m < 16; ++m) a[m] = 0.f;
#pragma unroll
  for (int l = 0; l < 4; ++l) {
    for (int c = 0; c < 32; ++c) {
      const float w = Wlin[(l * 32 + c) * 32 + o];
#pragma unroll
      for (int m = SLa[l]; m < ELa[l]; ++m) a[m] = fmaf(aggs[nl][c * 16 + m], w, a[m]);
    }
  }
  const float inv = a[0];
  float p2 = 0.f;
#pragma unroll
  for (int m = 0; m < 16; ++m) p2 = fmaf(a[m], a[m], p2);
  a[0] = inv + w2v[o] * p2 + w3v[o] * inv * p2;
#pragma unroll
  for (int m = 0; m < 16; ++m) bs[nl][o * 17 + m] = a[m];
  __syncthreads();
  float outv[16];
#pragma unroll
  for (int m = 0; m < 16; ++m) outv[m] = 0.f;
#pragma unroll
  for (int l = 0; l < 4; ++l) {
    for (int c = 0; c < 32; ++c) {
      const float w = Wprod[(l * 32 + c) * 32 + o];
#pragma unroll
      for (int m = SLa[l]; m < ELa[l]; ++m) outv[m] = fmaf(bs[nl][c * 17 + m], w, outv[m]);
    }
  }
  const int z = elem[n];
  const float* wsk = Wskip + z * 1024;
  for (int c = 0; c < 32; ++c) {
    const float w = wsk[c * 32 + o];
#pragma unroll
    for (int m = 0; m < 16; ++m) outv[m] = fmaf(nfs[nl][c * 16 + m], w, outv[m]);
  }
  float* op = nf + (size_t)n * 512 + o * 16;
  *(float4*)&op[0] = make_float4(outv[0], outv[1], outv[2], outv[3]);
  *(float4*)&op[4] = make_float4(outv[4], outv[5], outv[6], outv[7]);
  *(float4*)&op[8] = make_float4(outv[8], outv[9], outv[10], outv[11]);
  *(float4*)&op[12] = make_float4(outv[12], outv[13], outv[14], outv[15]);
  scal_out[n * 32 + o] = outv[0];
  dout[(size_t)n * 64 + layer * 32 + o] = outv[0];
}

extern "C" void kernel_launch(void* const* d_in, const int* in_sizes, int n_in,
                              void* d_out, int out_size, void* d_ws, size_t ws_size,
                              hipStream_t stream) {
  const float* pos = (const float*)d_in[0];
  const float* attrs = (const float*)d_in[1];
  const float* shifts = (const float*)d_in[2];
  const int* eidx = (const int*)d_in[3];
  const float* W_embed = (const float*)d_in[4];
  const float* W1 = (const float*)d_in[5];
  const float* W2 = (const float*)d_in[6];
  const float* W3 = (const float*)d_in[7];
  const float* W4 = (const float*)d_in[8];
  const float* Wlin = (const float*)d_in[9];
  const float* Wskip = (const float*)d_in[10];
  const float* w2v = (const float*)d_in[11];
  const float* w3v = (const float*)d_in[12];
  const float* Wprod = (const float*)d_in[13];
  float* out = (float*)d_out;
  const int* snd = eidx;
  const int* rcv = eidx + N_EDGES_C;

  char* p = (char*)d_ws;
  auto take = [&](size_t bytes) {
    char* q = p;
    p += (bytes + 255) & ~(size_t)255;
    return q;
  };
  int* counts = (int*)take((size_t)N_NODES_C * 4);
  int* row_start = (int*)take((size_t)(N_NODES_C + 1) * 4);
  int* cursor = (int*)take((size_t)N_NODES_C * 4);
  int* elist = (int*)take((size_t)N_EDGES_C * 4);
  int* elem = (int*)take((size_t)N_NODES_C * 4);
  float* Ybuf = (float*)take((size_t)(N_EDGES_C + 16) * 16 * 4);
  unsigned short* h3 = (unsigned short*)take((size_t)(N_EDGES_C + 16) * 128 * 2);
  float* sedge = (float*)take((size_t)(N_EDGES_C + 16) * 32 * 4);
  float* agg = (float*)take((size_t)N_NODES_C * 512 * 4);
  float* nf = (float*)take((size_t)N_NODES_C * 512 * 4);
  float* scal0 = (float*)take((size_t)N_NODES_C * 32 * 4);
  float* scal1 = (float*)take((size_t)N_NODES_C * 32 * 4);
  (void)ws_size; (void)in_sizes; (void)n_in; (void)out_size;

  hipMemsetAsync(counts, 0, (size_t)N_NODES_C * 4, stream);
  k_count<<<N_EDGES_C / 256, 256, 0, stream>>>(rcv, counts);
  k_scan<<<1, 1024, 0, stream>>>(counts, row_start, cursor);
  k_fill<<<N_EDGES_C / 256, 256, 0, stream>>>(rcv, cursor, elist);
  k_elem<<<N_NODES_C / 256, 256, 0, stream>>>(attrs, elem);
  k_embed<<<N_NODES_C * 32 / 256, 256, 0, stream>>>(attrs, W_embed, scal0, nf);

  for (int i = 0; i < 2; ++i) {
    k_radial<<<1536, 256, 0, stream>>>(pos, shifts, snd, rcv, elist,
                                       i == 0 ? scal0 : scal1,
                                       W1 + (size_t)i * 8 * 64, W2 + (size_t)i * 64 * 64,
                                       W3 + (size_t)i * 64 * 64, h3, sedge, Ybuf,
                                       i == 0 ? 1 : 0);
    k_gather<<<4096, 256, 0, stream>>>(h3, W4 + (size_t)i * 64 * 512, Ybuf, sedge,
                                       row_start, agg);
    k_node<<<N_NODES_C / 8, 256, 0, stream>>>(agg, nf, Wlin + (size_t)i * 4096,
                                              Wprod + (size_t)i * 4096,
                                              Wskip + (size_t)i * 8192,
                                              w2v + (size_t)i * 32, w3v + (size_t)i * 32,
                                              elem, scal1, out, i);
  }
}